// Round 5
// baseline (92.799 us; speedup 1.0000x reference)
//
#include <hip/hip_runtime.h>

#define NSEG 64
#define NROW 8192
#define WROW 21504
#define NBPP 576          // block slots per phase
#define T0   32           // phase-0 row tile
#define T12  16           // phase-1/2 row tile
#define PX0  132          // x0 LDS pitch
#define P1   196
#define P2   164
#define SBUF_FLOATS 4224  // max(32*132, 16*196, 16*164)

__global__ __launch_bounds__(256, 4) void iil_kernel(
    const float* __restrict__ x0, const float* __restrict__ x1, const float* __restrict__ x2,
    const float* __restrict__ w, const int* __restrict__ counts,
    float* __restrict__ y0, float* __restrict__ y1, float* __restrict__ y2)
{
    __shared__ float sbuf[SBUF_FLOATS];
    __shared__ int sstart[NSEG + 1];
    __shared__ int t16s[NSEG + 1];
    __shared__ int t32s[NSEG + 1];

    const int t = threadIdx.x;

    if (t < NSEG) {
        int c = counts[t];
        int v = c;
        #pragma unroll
        for (int d = 1; d < NSEG; d <<= 1) {
            int u = __shfl_up(v, d, 64);
            if (t >= d) v += u;
        }
        sstart[t + 1] = v;
        int a = (c + 15) >> 4;
        #pragma unroll
        for (int d = 1; d < NSEG; d <<= 1) {
            int u = __shfl_up(a, d, 64);
            if (t >= d) a += u;
        }
        t16s[t + 1] = a;
        int b2 = (c + 31) >> 5;
        #pragma unroll
        for (int d = 1; d < NSEG; d <<= 1) {
            int u = __shfl_up(b2, d, 64);
            if (t >= d) b2 += u;
        }
        t32s[t + 1] = b2;
        if (t == 0) { sstart[0] = 0; t16s[0] = 0; t32s[0] = 0; }
    }
    __syncthreads();

    const int phase = blockIdx.x % 3;          // interleave phases across dispatch order
    const int pb = blockIdx.x / 3;
    const float4 z4 = make_float4(0.f, 0.f, 0.f, 0.f);

    if (phase == 0) {
        if (pb >= t32s[NSEG]) return;
        int lo = 0, hi = NSEG;
        while (hi - lo > 1) {
            int mid = (lo + hi) >> 1;
            if (t32s[mid] <= pb) lo = mid; else hi = mid;
        }
        const int g = lo;
        const int s = sstart[g] + (pb - t32s[g]) * T0;
        const int nr = min(T0, sstart[g + 1] - s);
        const float* __restrict__ wseg = w + (size_t)g * WROW;

        const float4* g0 = (const float4*)x0 + (size_t)s * 32;
        #pragma unroll
        for (int i = 0; i < 4; ++i) {               // 1024 float4
            int idx = t + i * 256;
            int r = idx >> 5, c4 = idx & 31;
            float4 v = (r < nr) ? g0[idx] : z4;
            *(float4*)(sbuf + r * PX0 + c4 * 4) = v;
        }
        __syncthreads();

        const int og = t & 31;
        const int rg = t >> 5;
        const float* wp = wseg + og * 4;
        const float* xb = sbuf + rg * 4 * PX0;
        float acc[16];
        #pragma unroll
        for (int i = 0; i < 16; ++i) acc[i] = 0.f;

        float4 wA[4], xA[4], wB[4], xB[4];
#define LD0(WQ, XQ, KQ) do {                                      \
            const int k_ = (KQ) * 4;                              \
            WQ[0] = *(const float4*)(wp + (size_t)(k_ + 0) * 128);\
            WQ[1] = *(const float4*)(wp + (size_t)(k_ + 1) * 128);\
            WQ[2] = *(const float4*)(wp + (size_t)(k_ + 2) * 128);\
            WQ[3] = *(const float4*)(wp + (size_t)(k_ + 3) * 128);\
            XQ[0] = *(const float4*)(xb + 0 * PX0 + k_);          \
            XQ[1] = *(const float4*)(xb + 1 * PX0 + k_);          \
            XQ[2] = *(const float4*)(xb + 2 * PX0 + k_);          \
            XQ[3] = *(const float4*)(xb + 3 * PX0 + k_);          \
        } while (0)
#define RF0(J, XV, WQ)                                         \
            acc[J*4+0] = fmaf(XV.x, WQ[0].x, acc[J*4+0]);      \
            acc[J*4+1] = fmaf(XV.x, WQ[0].y, acc[J*4+1]);      \
            acc[J*4+2] = fmaf(XV.x, WQ[0].z, acc[J*4+2]);      \
            acc[J*4+3] = fmaf(XV.x, WQ[0].w, acc[J*4+3]);      \
            acc[J*4+0] = fmaf(XV.y, WQ[1].x, acc[J*4+0]);      \
            acc[J*4+1] = fmaf(XV.y, WQ[1].y, acc[J*4+1]);      \
            acc[J*4+2] = fmaf(XV.y, WQ[1].z, acc[J*4+2]);      \
            acc[J*4+3] = fmaf(XV.y, WQ[1].w, acc[J*4+3]);      \
            acc[J*4+0] = fmaf(XV.z, WQ[2].x, acc[J*4+0]);      \
            acc[J*4+1] = fmaf(XV.z, WQ[2].y, acc[J*4+1]);      \
            acc[J*4+2] = fmaf(XV.z, WQ[2].z, acc[J*4+2]);      \
            acc[J*4+3] = fmaf(XV.z, WQ[2].w, acc[J*4+3]);      \
            acc[J*4+0] = fmaf(XV.w, WQ[3].x, acc[J*4+0]);      \
            acc[J*4+1] = fmaf(XV.w, WQ[3].y, acc[J*4+1]);      \
            acc[J*4+2] = fmaf(XV.w, WQ[3].z, acc[J*4+2]);      \
            acc[J*4+3] = fmaf(XV.w, WQ[3].w, acc[J*4+3]);
#define CP0(WQ, XQ) { RF0(0, XQ[0], WQ) RF0(1, XQ[1], WQ) RF0(2, XQ[2], WQ) RF0(3, XQ[3], WQ) }

        LD0(wA, xA, 0);
        LD0(wB, xB, 1);
        #pragma unroll 1
        for (int kq = 0; kq < 30; kq += 2) {
            CP0(wA, xA);
            LD0(wA, xA, kq + 2);
            CP0(wB, xB);
            LD0(wB, xB, kq + 3);
        }
        CP0(wA, xA);
        CP0(wB, xB);
#undef LD0
#undef RF0
#undef CP0
        const float c0 = 0.011048543456039806f;  // 1/(8*sqrt(128))
        #pragma unroll
        for (int j = 0; j < 4; ++j) {
            int r = rg * 4 + j;
            if (r < nr) {
                *(float4*)(y0 + (size_t)(s + r) * 128 + og * 4) =
                    make_float4(acc[j*4+0] * c0, acc[j*4+1] * c0,
                                acc[j*4+2] * c0, acc[j*4+3] * c0);
            }
        }
    } else if (phase == 1) {
        if (pb >= t16s[NSEG]) return;
        int lo = 0, hi = NSEG;
        while (hi - lo > 1) {
            int mid = (lo + hi) >> 1;
            if (t16s[mid] <= pb) lo = mid; else hi = mid;
        }
        const int g = lo;
        const int s = sstart[g] + (pb - t16s[g]) * T12;
        const int nr = min(T12, sstart[g + 1] - s);
        const float* __restrict__ wseg = w + (size_t)g * WROW;

        float* sx1 = sbuf;
        const float4* g1 = (const float4*)x1 + (size_t)s * 48;
        #pragma unroll
        for (int i = 0; i < 3; ++i) {               // 768 float4
            int idx = t + i * 256;
            int r = idx / 48, c = idx - r * 48;
            float4 v = (r < nr) ? g1[idx] : z4;
            *(float4*)(sx1 + r * P1 + c * 4) = v;
        }
        __syncthreads();

        const int og = t & 15;
        const int r = t >> 4;
        const float* xrow = sx1 + r * P1;
        const float* wp = wseg + 16384 + og * 4;
        float acc[12];
        #pragma unroll
        for (int i = 0; i < 12; ++i) acc[i] = 0.f;

        float4 wA[4], wB[4];
#define LD1(WQ, KQ) do {                                              \
            WQ[0] = *(const float4*)(wp + (size_t)((KQ)*4 + 0) * 64); \
            WQ[1] = *(const float4*)(wp + (size_t)((KQ)*4 + 1) * 64); \
            WQ[2] = *(const float4*)(wp + (size_t)((KQ)*4 + 2) * 64); \
            WQ[3] = *(const float4*)(wp + (size_t)((KQ)*4 + 3) * 64); \
        } while (0)
#define CP1(WQ, KQ) do {                                              \
            float4 xq0 = *(const float4*)(xrow + 12 * (KQ) + 0);      \
            float4 xq1 = *(const float4*)(xrow + 12 * (KQ) + 4);      \
            float4 xq2 = *(const float4*)(xrow + 12 * (KQ) + 8);      \
            float xf[12] = {xq0.x, xq0.y, xq0.z, xq0.w,               \
                            xq1.x, xq1.y, xq1.z, xq1.w,               \
                            xq2.x, xq2.y, xq2.z, xq2.w};              \
            _Pragma("unroll")                                         \
            for (int kk = 0; kk < 4; ++kk) {                          \
                float4 wv = WQ[kk];                                   \
                acc[0]  = fmaf(wv.x, xf[kk*3+0], acc[0]);             \
                acc[1]  = fmaf(wv.x, xf[kk*3+1], acc[1]);             \
                acc[2]  = fmaf(wv.x, xf[kk*3+2], acc[2]);             \
                acc[3]  = fmaf(wv.y, xf[kk*3+0], acc[3]);             \
                acc[4]  = fmaf(wv.y, xf[kk*3+1], acc[4]);             \
                acc[5]  = fmaf(wv.y, xf[kk*3+2], acc[5]);             \
                acc[6]  = fmaf(wv.z, xf[kk*3+0], acc[6]);             \
                acc[7]  = fmaf(wv.z, xf[kk*3+1], acc[7]);             \
                acc[8]  = fmaf(wv.z, xf[kk*3+2], acc[8]);             \
                acc[9]  = fmaf(wv.w, xf[kk*3+0], acc[9]);             \
                acc[10] = fmaf(wv.w, xf[kk*3+1], acc[10]);            \
                acc[11] = fmaf(wv.w, xf[kk*3+2], acc[11]);            \
            }                                                         \
        } while (0)

        LD1(wA, 0);
        LD1(wB, 1);
        #pragma unroll 1
        for (int kq = 0; kq < 14; kq += 2) {
            CP1(wA, kq);
            LD1(wA, kq + 2);
            CP1(wB, kq + 1);
            LD1(wB, kq + 3);
        }
        CP1(wA, 14);
        CP1(wB, 15);
#undef LD1
#undef CP1
        const float c1 = 0.015625f;      // 1/(8*8)
        if (r < nr) {
            float* yb = y1 + (size_t)(s + r) * 192 + og * 12;
            *(float4*)(yb + 0) = make_float4(acc[0] * c1, acc[1] * c1, acc[2] * c1, acc[3] * c1);
            *(float4*)(yb + 4) = make_float4(acc[4] * c1, acc[5] * c1, acc[6] * c1, acc[7] * c1);
            *(float4*)(yb + 8) = make_float4(acc[8] * c1, acc[9] * c1, acc[10] * c1, acc[11] * c1);
        }
    } else {
        if (pb >= t16s[NSEG]) return;
        int lo = 0, hi = NSEG;
        while (hi - lo > 1) {
            int mid = (lo + hi) >> 1;
            if (t16s[mid] <= pb) lo = mid; else hi = mid;
        }
        const int g = lo;
        const int s = sstart[g] + (pb - t16s[g]) * T12;
        const int nr = min(T12, sstart[g + 1] - s);
        const float* __restrict__ wseg = w + (size_t)g * WROW;

        float* sx2 = sbuf;
        const float4* g2 = (const float4*)x2 + (size_t)s * 40;
        #pragma unroll
        for (int i = 0; i < 3; ++i) {               // 640 float4
            int idx = t + i * 256;
            if (idx < 640) {
                int r = idx / 40, c = idx - r * 40;
                float4 v = (r < nr) ? g2[idx] : z4;
                *(float4*)(sx2 + r * P2 + c * 4) = v;
            }
        }
        __syncthreads();

        const int og = t & 15;
        const int r = t >> 4;
        const float* xrow = sx2 + r * P2;
        const float* wp = wseg + 20480 + og * 2;
        float acc[10];
        #pragma unroll
        for (int i = 0; i < 10; ++i) acc[i] = 0.f;

        float2 wA[4], wB[4];
#define LD2(WQ, KQ) do {                                              \
            WQ[0] = *(const float2*)(wp + (size_t)((KQ)*4 + 0) * 32); \
            WQ[1] = *(const float2*)(wp + (size_t)((KQ)*4 + 1) * 32); \
            WQ[2] = *(const float2*)(wp + (size_t)((KQ)*4 + 2) * 32); \
            WQ[3] = *(const float2*)(wp + (size_t)((KQ)*4 + 3) * 32); \
        } while (0)
#define CP2(WQ, KQ) do {                                              \
            float xf[20];                                             \
            _Pragma("unroll")                                         \
            for (int j = 0; j < 5; ++j) {                             \
                float4 v = *(const float4*)(xrow + 20 * (KQ) + 4 * j);\
                xf[4*j+0] = v.x; xf[4*j+1] = v.y;                     \
                xf[4*j+2] = v.z; xf[4*j+3] = v.w;                     \
            }                                                         \
            _Pragma("unroll")                                         \
            for (int kk = 0; kk < 4; ++kk) {                          \
                float2 wv = WQ[kk];                                   \
                _Pragma("unroll")                                     \
                for (int i = 0; i < 5; ++i) {                         \
                    acc[i]     = fmaf(wv.x, xf[5*kk+i], acc[i]);      \
                    acc[5 + i] = fmaf(wv.y, xf[5*kk+i], acc[5 + i]);  \
                }                                                     \
            }                                                         \
        } while (0)

        LD2(wA, 0);
        LD2(wB, 1);
        #pragma unroll 1
        for (int kq = 0; kq < 6; kq += 2) {
            CP2(wA, kq);
            LD2(wA, kq + 2);
            CP2(wB, kq + 1);
            LD2(wB, kq + 3);
        }
        CP2(wA, 6);
        CP2(wB, 7);
#undef LD2
#undef CP2
        const float c2 = 0.022097086912079608f;  // 1/(8*sqrt(32))
        if (r < nr) {
            float* yb = y2 + (size_t)(s + r) * 160 + og * 10;
            #pragma unroll
            for (int i = 0; i < 5; ++i)
                *(float2*)(yb + 2 * i) = make_float2(acc[2 * i] * c2, acc[2 * i + 1] * c2);
        }
    }
}

extern "C" void kernel_launch(void* const* d_in, const int* in_sizes, int n_in,
                              void* d_out, int out_size, void* d_ws, size_t ws_size,
                              hipStream_t stream) {
    const float* x0 = (const float*)d_in[0];
    const float* x1 = (const float*)d_in[1];
    const float* x2 = (const float*)d_in[2];
    const float* w  = (const float*)d_in[3];
    const int* counts = (const int*)d_in[4];

    float* y0 = (float*)d_out;
    float* y1 = y0 + (size_t)NROW * 128;
    float* y2 = y1 + (size_t)NROW * 192;

    hipLaunchKernelGGL(iil_kernel, dim3(3 * NBPP), dim3(256), 0, stream,
                       x0, x1, x2, w, counts, y0, y1, y2);
}